// Round 2
// baseline (472.763 us; speedup 1.0000x reference)
//
#include <hip/hip_runtime.h>
#include <hip/hip_bf16.h>
#include <cmath>

// Problem constants
#define B_DIM 4
#define T_DIM 2048
#define D_DIM 1024
#define M_DIM 8192          // B*T
#define KP    2048          // physical K (hi|lo) per operand row
#define NKT   48            // 3072 / 64 k-tiles (3 segments x 16)

#define NCH   64            // scan chunks
#define CHL   32            // T / NCH

using bf16 = __hip_bfloat16;
typedef __attribute__((ext_vector_type(8))) short frag8;   // 8 bf16 (4 VGPRs)
typedef __attribute__((ext_vector_type(4))) float f32x4;   // MFMA accumulator

// ---------------- workspace layout (bytes) ----------------
// Xs (8192x2048 bf16, aliased by Hs after GEMM1)  33,554,432
// Wins (2048x2048 bf16)                            8,388,608
// Wss  (1024x2048 bf16)                            4,194,304
// Wos  (1024x2048 bf16)                            4,194,304
// gatef (8192x1024 f32)                           33,554,432
// Vs   (8192x2048 bf16)                           33,554,432
// af   (8192x1024 f32)                            33,554,432
// bf   (8192x1024 f32)                            33,554,432
// Ach/Bch/carry (64*4096 f32 each)                 3,145,728
// total ~187.7 MB
#define XS_OFF   0L
#define WIN_OFF  33554432L
#define WSS_OFF  41943040L
#define WOS_OFF  46137344L
#define GATE_OFF 50331648L
#define VS_OFF   83886080L
#define AF_OFF   117440512L
#define BF_OFF   150994944L
#define ACH_OFF  184549376L
#define BCH_OFF  185597952L
#define CAR_OFF  186646528L

// ---------------- hi/lo split convert (vectorized: 4 f32/thread) ----------------
// src: [rows][1024] f32  ->  dst: [rows][2048] bf16 with hi at col, lo at col+1024
__global__ void split_kernel(const float* __restrict__ src, bf16* __restrict__ dst, long total4) {
    long i4 = (long)blockIdx.x * blockDim.x + threadIdx.x;
    if (i4 >= total4) return;
    long i = i4 * 4;                       // element index, 1024 | 4 so same row
    const float4 v = *(const float4*)&src[i];
    long r = i >> 10;
    int  c = (int)(i & 1023);
    ushort hi[4], lo[4];
    const float vv[4] = {v.x, v.y, v.z, v.w};
#pragma unroll
    for (int j = 0; j < 4; ++j) {
        bf16 h = __float2bfloat16(vv[j]);
        hi[j] = *(ushort*)&h;
        bf16 l2 = __float2bfloat16(vv[j] - __bfloat162float(h));
        lo[j] = *(ushort*)&l2;
    }
    *(ushort4*)&dst[r * KP + c]        = make_ushort4(hi[0], hi[1], hi[2], hi[3]);
    *(ushort4*)&dst[r * KP + c + 1024] = make_ushort4(lo[0], lo[1], lo[2], lo[3]);
}

// ---------------- split-K bf16 GEMM (m97 structure) ----------------
// C[m,n] = sum_{k'} A'[m,k'] * B'[n,k'] over K'=3072 where
//   A' segs = [hi, hi, lo]  (physical A: [M][2048] = [hi|lo])
//   B' segs = [hi, lo, hi]  (physical B: [N][2048] = [hi|lo])
// EPI 1: gv=acc+b_in[n]; n<1024 -> gatef=sigmoid; n>=1024 -> Vs hi/lo split
// EPI 2: sv=tanh(acc+b_s[n]); af=1-g; bf=g*sv
// EPI 3: out = x + acc + b_o[n]
template<int EPI>
__global__ __launch_bounds__(256)
void gemm_split(const bf16* __restrict__ A, const bf16* __restrict__ Bw,
                const float* __restrict__ bias,
                const float* __restrict__ gatef_in,
                const float* __restrict__ x_in,
                float* __restrict__ out0, float* __restrict__ out1,
                bf16* __restrict__ outv)
{
    __shared__ bf16 As[128 * 64];
    __shared__ bf16 Bs[128 * 64];
    const int t  = threadIdx.x;
    const int bm = blockIdx.x;
    const int bn = blockIdx.y;
    const int w  = t >> 6;
    const int l  = t & 63;
    const int wr = w >> 1, wc = w & 1;

    f32x4 acc[4][4] = {};

    const int rowA0 = t >> 3;          // + i*32 : row within 128-tile
    const int colA0 = (t & 7) * 8;     // bf16 col within 64-wide k-tile

    const bf16* Abase = A  + (long)bm * 128 * KP;
    const bf16* Bbase = Bw + (long)bn * 128 * KP;

    for (int kt = 0; kt < NKT; ++kt) {
        const int seg    = kt >> 4;
        const int within = kt & 15;
        const int ka = (seg == 2 ? 1024 : 0) + within * 64 + colA0;  // A: [hi,hi,lo]
        const int kb = (seg == 1 ? 1024 : 0) + within * 64 + colA0;  // B: [hi,lo,hi]
        __syncthreads();   // previous iteration's LDS reads done
#pragma unroll
        for (int i = 0; i < 4; ++i) {
            const bf16* ga = Abase + (long)(rowA0 + i * 32) * KP + ka;
            __builtin_amdgcn_global_load_lds(
                (const __attribute__((address_space(1))) void*)ga,
                (__attribute__((address_space(3))) void*)&As[(i * 256 + t) * 8],
                16, 0, 0);
        }
#pragma unroll
        for (int i = 0; i < 4; ++i) {
            const bf16* gb = Bbase + (long)(rowA0 + i * 32) * KP + kb;
            __builtin_amdgcn_global_load_lds(
                (const __attribute__((address_space(1))) void*)gb,
                (__attribute__((address_space(3))) void*)&Bs[(i * 256 + t) * 8],
                16, 0, 0);
        }
        asm volatile("s_waitcnt vmcnt(0)" ::: "memory");
        __syncthreads();
#pragma unroll
        for (int kk = 0; kk < 2; ++kk) {
            frag8 fa[4], fb[4];
            const int kbase = kk * 32 + (l >> 4) * 8;
#pragma unroll
            for (int f = 0; f < 4; ++f) {
                fa[f] = *(const frag8*)&As[(wr * 64 + f * 16 + (l & 15)) * 64 + kbase];
                fb[f] = *(const frag8*)&Bs[(wc * 64 + f * 16 + (l & 15)) * 64 + kbase];
            }
#pragma unroll
            for (int fm = 0; fm < 4; ++fm)
#pragma unroll
                for (int fn = 0; fn < 4; ++fn)
                    acc[fm][fn] = __builtin_amdgcn_mfma_f32_16x16x32_bf16(
                        fa[fm], fb[fn], acc[fm][fn], 0, 0, 0);
        }
    }

    // epilogue: C/D layout col=lane&15, row=(lane>>4)*4+j  [m89-verified]
    const int r4 = (l >> 4) * 4;
    const int cl = l & 15;
#pragma unroll
    for (int fm = 0; fm < 4; ++fm) {
#pragma unroll
        for (int fn = 0; fn < 4; ++fn) {
            const int n = bn * 128 + wc * 64 + fn * 16 + cl;
            const float bn_bias = bias[n];
#pragma unroll
            for (int j = 0; j < 4; ++j) {
                const int m = bm * 128 + wr * 64 + fm * 16 + r4 + j;
                float v = acc[fm][fn][j] + bn_bias;
                if (EPI == 1) {
                    if (n < 1024) {
                        out0[(long)m * 1024 + n] = 1.0f / (1.0f + expf(-v));
                    } else {
                        bf16 h = __float2bfloat16(v);
                        float lof = v - __bfloat162float(h);
                        const int d = n - 1024;
                        outv[(long)m * KP + d]        = h;
                        outv[(long)m * KP + d + 1024] = __float2bfloat16(lof);
                    }
                } else if (EPI == 2) {
                    const float sv = tanhf(v);
                    const float g  = gatef_in[(long)m * 1024 + n];
                    out0[(long)m * 1024 + n] = 1.0f - g;
                    out1[(long)m * 1024 + n] = g * sv;
                } else {
                    out0[(long)m * 1024 + n] = x_in[(long)m * 1024 + n] + v;
                }
            }
        }
    }
}

// ---------------- chunked parallel scan: h[t] = a[t]*h[t-1] + b[t] ----------------
__global__ void scan_phase1(const float* __restrict__ af, const float* __restrict__ bfv,
                            float* __restrict__ Ach, float* __restrict__ Bch) {
    int tid = blockIdx.x * 256 + threadIdx.x;   // [chunk][b][d]
    int c = tid >> 12;
    int r = tid & 4095;
    int bi = r >> 10;
    long base = ((long)bi * T_DIM + c * CHL) * D_DIM + (r & 1023);
    float A = 1.0f, Bc = 0.0f;
#pragma unroll 4
    for (int i = 0; i < CHL; ++i) {
        float a = af[base + (long)i * D_DIM];
        float b = bfv[base + (long)i * D_DIM];
        A *= a;
        Bc = a * Bc + b;
    }
    Ach[tid] = A;
    Bch[tid] = Bc;
}

__global__ void scan_phase2(const float* __restrict__ Ach, const float* __restrict__ Bch,
                            float* __restrict__ carry) {
    int r = blockIdx.x * 256 + threadIdx.x;   // 0..4095
    float h = 0.0f;
#pragma unroll
    for (int c = 0; c < NCH; ++c) {
        carry[c * 4096 + r] = h;
        h = Ach[c * 4096 + r] * h + Bch[c * 4096 + r];
    }
}

__global__ void scan_phase3(const float* __restrict__ af, const float* __restrict__ bfv,
                            const float* __restrict__ carry, bf16* __restrict__ Hs) {
    int tid = blockIdx.x * 256 + threadIdx.x;
    int c = tid >> 12;
    int r = tid & 4095;
    int bi = r >> 10;
    int d  = r & 1023;
    long base = ((long)bi * T_DIM + c * CHL) * D_DIM + d;
    float h = carry[tid];
#pragma unroll 4
    for (int i = 0; i < CHL; ++i) {
        float a = af[base + (long)i * D_DIM];
        float b = bfv[base + (long)i * D_DIM];
        h = a * h + b;
        long m = (long)bi * T_DIM + c * CHL + i;
        bf16 hh = __float2bfloat16(h);
        float lof = h - __bfloat162float(hh);
        Hs[m * KP + d]        = hh;
        Hs[m * KP + d + 1024] = __float2bfloat16(lof);
    }
}

// ---------------- launch ----------------
extern "C" void kernel_launch(void* const* d_in, const int* in_sizes, int n_in,
                              void* d_out, int out_size, void* d_ws, size_t ws_size,
                              hipStream_t stream) {
    const float* x   = (const float*)d_in[0];
    const float* Win = (const float*)d_in[1];
    const float* bin = (const float*)d_in[2];
    const float* Wsm = (const float*)d_in[3];
    const float* bs  = (const float*)d_in[4];
    const float* Wo  = (const float*)d_in[5];
    const float* bo  = (const float*)d_in[6];
    float* out = (float*)d_out;
    char*  ws  = (char*)d_ws;

    bf16*  Xs    = (bf16*)(ws + XS_OFF);   // also Hs after GEMM1 consumes Xs
    bf16*  Wins  = (bf16*)(ws + WIN_OFF);
    bf16*  Wss   = (bf16*)(ws + WSS_OFF);
    bf16*  Wos   = (bf16*)(ws + WOS_OFF);
    float* gatef = (float*)(ws + GATE_OFF);
    bf16*  Vs    = (bf16*)(ws + VS_OFF);
    float* af    = (float*)(ws + AF_OFF);
    float* bfv   = (float*)(ws + BF_OFF);
    float* Ach   = (float*)(ws + ACH_OFF);
    float* Bch   = (float*)(ws + BCH_OFF);
    float* car   = (float*)(ws + CAR_OFF);

    // hi/lo split converts (4 f32 per thread)
    split_kernel<<<(M_DIM * D_DIM / 4 + 255) / 256, 256, 0, stream>>>(x,   Xs,   (long)M_DIM * D_DIM / 4);
    split_kernel<<<(2048 * 1024 / 4 + 255) / 256,  256, 0, stream>>>(Win, Wins, 2048L * 1024 / 4);
    split_kernel<<<(1024 * 1024 / 4 + 255) / 256,  256, 0, stream>>>(Wsm, Wss,  1024L * 1024 / 4);
    split_kernel<<<(1024 * 1024 / 4 + 255) / 256,  256, 0, stream>>>(Wo,  Wos,  1024L * 1024 / 4);

    // GEMM1: gv = x @ W_in^T ; gate/val epilogue
    dim3 g1(M_DIM / 128, 2048 / 128);
    gemm_split<1><<<g1, 256, 0, stream>>>(Xs, Wins, bin, nullptr, nullptr, gatef, nullptr, Vs);

    // GEMM2: sv = tanh(val @ W_s^T) ; a,b epilogue
    dim3 g2(M_DIM / 128, 1024 / 128);
    gemm_split<2><<<g2, 256, 0, stream>>>(Vs, Wss, bs, gatef, nullptr, af, bfv, nullptr);

    // scan: h[t] = a[t]*h[t-1] + b[t]
    scan_phase1<<<NCH * 4096 / 256, 256, 0, stream>>>(af, bfv, Ach, Bch);
    scan_phase2<<<4096 / 256, 256, 0, stream>>>(Ach, Bch, car);
    scan_phase3<<<NCH * 4096 / 256, 256, 0, stream>>>(af, bfv, car, Xs /*Hs*/);

    // GEMM3: out = x + h @ W_o^T + b_o
    gemm_split<3><<<g2, 256, 0, stream>>>(Xs, Wos, bo, nullptr, x, out, nullptr, nullptr);
}

// Round 4
// 398.772 us; speedup vs baseline: 1.1855x; 1.1855x over previous
//
#include <hip/hip_runtime.h>
#include <hip/hip_bf16.h>
#include <cmath>

// Problem constants
#define B_DIM 4
#define T_DIM 2048
#define D_DIM 1024
#define M_DIM 8192          // B*T
#define KP    2048          // physical K per activation row: [hi|lo]
#define NKT   32            // K'=2048 / 64 k-tiles (2 segments x 16)

#define NCH   64            // scan chunks
#define CHL   32            // T / NCH

using bf16 = __hip_bfloat16;
typedef __attribute__((ext_vector_type(8))) short frag8;   // 8 bf16 (4 VGPRs)
typedef __attribute__((ext_vector_type(4))) float f32x4;   // MFMA accumulator

// ---------------- workspace layout (bytes) ----------------
#define XS_OFF   0L
#define WIN_OFF  33554432L
#define WSS_OFF  37748736L
#define WOS_OFF  39845888L
#define GATE_OFF 41943040L
#define VS_OFF   75497472L
#define AF_OFF   109051904L
#define BF_OFF   142606336L
#define ACH_OFF  176160768L
#define BCH_OFF  177209344L
#define CAR_OFF  178257920L

// ---------------- hi/lo split convert for activations (4 f32/thread) ----------------
// src: [rows][1024] f32 -> dst: [rows][2048] bf16, hi at col, lo at col+1024
__global__ void split_kernel(const float* __restrict__ src, bf16* __restrict__ dst, long total4) {
    long i4 = (long)blockIdx.x * blockDim.x + threadIdx.x;
    if (i4 >= total4) return;
    long i = i4 * 4;
    const float4 v = *(const float4*)&src[i];
    long r = i >> 10;
    int  c = (int)(i & 1023);
    ushort hi[4], lo[4];
    const float vv[4] = {v.x, v.y, v.z, v.w};
#pragma unroll
    for (int j = 0; j < 4; ++j) {
        bf16 h = __float2bfloat16(vv[j]);
        hi[j] = *(ushort*)&h;
        bf16 l2 = __float2bfloat16(vv[j] - __bfloat162float(h));
        lo[j] = *(ushort*)&l2;
    }
    *(ushort4*)&dst[r * KP + c]        = make_ushort4(hi[0], hi[1], hi[2], hi[3]);
    *(ushort4*)&dst[r * KP + c + 1024] = make_ushort4(lo[0], lo[1], lo[2], lo[3]);
}

// weights: plain RN-bf16 convert, [N][1024] hi-only
__global__ void split_hi_kernel(const float* __restrict__ src, bf16* __restrict__ dst, long total4) {
    long i4 = (long)blockIdx.x * blockDim.x + threadIdx.x;
    if (i4 >= total4) return;
    long i = i4 * 4;
    const float4 v = *(const float4*)&src[i];
    bf16 h0 = __float2bfloat16(v.x), h1 = __float2bfloat16(v.y);
    bf16 h2 = __float2bfloat16(v.z), h3 = __float2bfloat16(v.w);
    *(ushort4*)&dst[i] = make_ushort4(*(ushort*)&h0, *(ushort*)&h1, *(ushort*)&h2, *(ushort*)&h3);
}

// ---------------- split-K bf16 GEMM, 2-phase dbuf + counted vmcnt ----------------
// C[m,n] = sum_{k'=0..2047} A[m,k'] * Bhi[n, k' mod 1024]
//   A physical [M][2048] = [hi|lo]  -> (hi_a + lo_a) . hi_b  (drops hi_a*lo_b, ~1e-3)
// EPI 1: gv=acc+b_in[n]; n<1024 -> gatef=sigmoid; n>=1024 -> Vs hi/lo split
// EPI 2: sv=tanh(acc+b_s[n]); af=1-g; bf=g*sv
// EPI 3: out = x + acc + b_o[n]
template<int EPI>
__global__ __launch_bounds__(256)
void gemm_split(const bf16* __restrict__ A, const bf16* __restrict__ Bw,
                const float* __restrict__ bias,
                const float* __restrict__ gatef_in,
                const float* __restrict__ x_in,
                float* __restrict__ out0, float* __restrict__ out1,
                bf16* __restrict__ outv)
{
    __shared__ bf16 As[2][128 * 64];
    __shared__ bf16 Bs[2][128 * 64];
    const int t  = threadIdx.x;
    const int bm = blockIdx.x;
    const int bn = blockIdx.y;
    const int w  = t >> 6;
    const int l  = t & 63;
    const int wr = w >> 1, wc = w & 1;

    f32x4 acc[4][4] = {};

    const int rowA0 = t >> 3;          // + i*32 : row within 128-tile
    const int colA0 = (t & 7) * 8;     // bf16 col within 64-wide k-tile

    const bf16* Abase = A  + (long)bm * 128 * KP;
    const bf16* Bbase = Bw + (long)bn * 128 * 1024;

#define STAGE(buf, kt)                                                          \
    {                                                                           \
        const int ka = (kt) * 64 + colA0;              /* 0..2047 linear */     \
        const int kb = ((kt) & 15) * 64 + colA0;       /* hi reread     */      \
        _Pragma("unroll")                                                       \
        for (int i = 0; i < 4; ++i) {                                           \
            const bf16* ga = Abase + (long)(rowA0 + i * 32) * KP + ka;          \
            __builtin_amdgcn_global_load_lds(                                   \
                (const __attribute__((address_space(1))) void*)ga,              \
                (__attribute__((address_space(3))) void*)&As[buf][(i * 256 + t) * 8], \
                16, 0, 0);                                                      \
        }                                                                       \
        _Pragma("unroll")                                                       \
        for (int i = 0; i < 4; ++i) {                                           \
            const bf16* gb = Bbase + (long)(rowA0 + i * 32) * 1024 + kb;        \
            __builtin_amdgcn_global_load_lds(                                   \
                (const __attribute__((address_space(1))) void*)gb,              \
                (__attribute__((address_space(3))) void*)&Bs[buf][(i * 256 + t) * 8], \
                16, 0, 0);                                                      \
        }                                                                       \
    }

    STAGE(0, 0);                       // prologue: 8 loads in flight

    for (int kt = 0; kt < NKT; ++kt) {
        const int cur = kt & 1;
        if (kt + 1 < NKT) {
            STAGE(cur ^ 1, kt + 1);    // issue next tile's 8 loads
            asm volatile("s_waitcnt vmcnt(8)" ::: "memory");   // cur's loads done
        } else {
            asm volatile("s_waitcnt vmcnt(0)" ::: "memory");
        }
        __builtin_amdgcn_s_barrier();
        asm volatile("" ::: "memory");
#pragma unroll
        for (int kk = 0; kk < 2; ++kk) {
            frag8 fa[4], fb[4];
            const int kbase = kk * 32 + (l >> 4) * 8;
#pragma unroll
            for (int f = 0; f < 4; ++f) {
                fa[f] = *(const frag8*)&As[cur][(wr * 64 + f * 16 + (l & 15)) * 64 + kbase];
                fb[f] = *(const frag8*)&Bs[cur][(wc * 64 + f * 16 + (l & 15)) * 64 + kbase];
            }
#pragma unroll
            for (int fm = 0; fm < 4; ++fm)
#pragma unroll
                for (int fn = 0; fn < 4; ++fn)
                    acc[fm][fn] = __builtin_amdgcn_mfma_f32_16x16x32_bf16(
                        fa[fm], fb[fn], acc[fm][fn], 0, 0, 0);
        }
        asm volatile("" ::: "memory");
        __builtin_amdgcn_s_barrier();  // all waves done reading cur before overwrite
        asm volatile("" ::: "memory");
    }
#undef STAGE

    // epilogue: C/D layout col=lane&15, row=(lane>>4)*4+j  [m89-verified]
    const int r4 = (l >> 4) * 4;
    const int cl = l & 15;
#pragma unroll
    for (int fm = 0; fm < 4; ++fm) {
#pragma unroll
        for (int fn = 0; fn < 4; ++fn) {
            const int n = bn * 128 + wc * 64 + fn * 16 + cl;
            const float bn_bias = bias[n];
#pragma unroll
            for (int j = 0; j < 4; ++j) {
                const int m = bm * 128 + wr * 64 + fm * 16 + r4 + j;
                float v = acc[fm][fn][j] + bn_bias;
                if (EPI == 1) {
                    if (n < 1024) {
                        out0[(long)m * 1024 + n] = 1.0f / (1.0f + expf(-v));
                    } else {
                        bf16 h = __float2bfloat16(v);
                        float lof = v - __bfloat162float(h);
                        const int d = n - 1024;
                        outv[(long)m * KP + d]        = h;
                        outv[(long)m * KP + d + 1024] = __float2bfloat16(lof);
                    }
                } else if (EPI == 2) {
                    const float sv = tanhf(v);
                    const float g  = gatef_in[(long)m * 1024 + n];
                    out0[(long)m * 1024 + n] = 1.0f - g;
                    out1[(long)m * 1024 + n] = g * sv;
                } else {
                    out0[(long)m * 1024 + n] = x_in[(long)m * 1024 + n] + v;
                }
            }
        }
    }
}

// ---------------- chunked parallel scan: h[t] = a[t]*h[t-1] + b[t] ----------------
__global__ void scan_phase1(const float* __restrict__ af, const float* __restrict__ bfv,
                            float* __restrict__ Ach, float* __restrict__ Bch) {
    int tid = blockIdx.x * 256 + threadIdx.x;   // [chunk][b][d]
    int c = tid >> 12;
    int r = tid & 4095;
    int bi = r >> 10;
    long base = ((long)bi * T_DIM + c * CHL) * D_DIM + (r & 1023);
    float A = 1.0f, Bc = 0.0f;
#pragma unroll 4
    for (int i = 0; i < CHL; ++i) {
        float a = af[base + (long)i * D_DIM];
        float b = bfv[base + (long)i * D_DIM];
        A *= a;
        Bc = a * Bc + b;
    }
    Ach[tid] = A;
    Bch[tid] = Bc;
}

__global__ void scan_phase2(const float* __restrict__ Ach, const float* __restrict__ Bch,
                            float* __restrict__ carry) {
    int r = blockIdx.x * 256 + threadIdx.x;   // 0..4095
    float h = 0.0f;
#pragma unroll
    for (int c = 0; c < NCH; ++c) {
        carry[c * 4096 + r] = h;
        h = Ach[c * 4096 + r] * h + Bch[c * 4096 + r];
    }
}

__global__ void scan_phase3(const float* __restrict__ af, const float* __restrict__ bfv,
                            const float* __restrict__ carry, bf16* __restrict__ Hs) {
    int tid = blockIdx.x * 256 + threadIdx.x;
    int c = tid >> 12;
    int r = tid & 4095;
    int bi = r >> 10;
    int d  = r & 1023;
    long base = ((long)bi * T_DIM + c * CHL) * D_DIM + d;
    float h = carry[tid];
#pragma unroll 4
    for (int i = 0; i < CHL; ++i) {
        float a = af[base + (long)i * D_DIM];
        float b = bfv[base + (long)i * D_DIM];
        h = a * h + b;
        long m = (long)bi * T_DIM + c * CHL + i;
        bf16 hh = __float2bfloat16(h);
        float lof = h - __bfloat162float(hh);
        Hs[m * KP + d]        = hh;
        Hs[m * KP + d + 1024] = __float2bfloat16(lof);
    }
}

// ---------------- launch ----------------
extern "C" void kernel_launch(void* const* d_in, const int* in_sizes, int n_in,
                              void* d_out, int out_size, void* d_ws, size_t ws_size,
                              hipStream_t stream) {
    const float* x   = (const float*)d_in[0];
    const float* Win = (const float*)d_in[1];
    const float* bin = (const float*)d_in[2];
    const float* Wsm = (const float*)d_in[3];
    const float* bs  = (const float*)d_in[4];
    const float* Wo  = (const float*)d_in[5];
    const float* bo  = (const float*)d_in[6];
    float* out = (float*)d_out;
    char*  ws  = (char*)d_ws;

    bf16*  Xs    = (bf16*)(ws + XS_OFF);   // also Hs after GEMM1 consumes Xs
    bf16*  Wins  = (bf16*)(ws + WIN_OFF);
    bf16*  Wss   = (bf16*)(ws + WSS_OFF);
    bf16*  Wos   = (bf16*)(ws + WOS_OFF);
    float* gatef = (float*)(ws + GATE_OFF);
    bf16*  Vs    = (bf16*)(ws + VS_OFF);
    float* af    = (float*)(ws + AF_OFF);
    float* bfv   = (float*)(ws + BF_OFF);
    float* Ach   = (float*)(ws + ACH_OFF);
    float* Bch   = (float*)(ws + BCH_OFF);
    float* car   = (float*)(ws + CAR_OFF);

    // activation split (hi|lo) and weight converts (hi only)
    split_kernel   <<<(M_DIM * D_DIM / 4 + 255) / 256, 256, 0, stream>>>(x,   Xs,   (long)M_DIM * D_DIM / 4);
    split_hi_kernel<<<(2048 * 1024 / 4 + 255) / 256,  256, 0, stream>>>(Win, Wins, 2048L * 1024 / 4);
    split_hi_kernel<<<(1024 * 1024 / 4 + 255) / 256,  256, 0, stream>>>(Wsm, Wss,  1024L * 1024 / 4);
    split_hi_kernel<<<(1024 * 1024 / 4 + 255) / 256,  256, 0, stream>>>(Wo,  Wos,  1024L * 1024 / 4);

    // GEMM1: gv = x @ W_in^T ; gate/val epilogue
    dim3 g1(M_DIM / 128, 2048 / 128);
    gemm_split<1><<<g1, 256, 0, stream>>>(Xs, Wins, bin, nullptr, nullptr, gatef, nullptr, Vs);

    // GEMM2: sv = tanh(val @ W_s^T) ; a,b epilogue
    dim3 g2(M_DIM / 128, 1024 / 128);
    gemm_split<2><<<g2, 256, 0, stream>>>(Vs, Wss, bs, gatef, nullptr, af, bfv, nullptr);

    // scan: h[t] = a[t]*h[t-1] + b[t]
    scan_phase1<<<NCH * 4096 / 256, 256, 0, stream>>>(af, bfv, Ach, Bch);
    scan_phase2<<<4096 / 256, 256, 0, stream>>>(Ach, Bch, car);
    scan_phase3<<<NCH * 4096 / 256, 256, 0, stream>>>(af, bfv, car, Xs /*Hs*/);

    // GEMM3: out = x + h @ W_o^T + b_o
    gemm_split<3><<<g2, 256, 0, stream>>>(Xs, Wos, bo, nullptr, x, out, nullptr, nullptr);
}